// Round 4
// baseline (509.985 us; speedup 1.0000x reference)
//
#include <hip/hip_runtime.h>
#include <stdint.h>

typedef unsigned short u16;
typedef __attribute__((ext_vector_type(4))) float f32x4;
typedef __attribute__((ext_vector_type(8))) short s16x8;

#define BATCH 4
#define SEQ   2048
#define DIM   1024   // D_IN = STATE = D_OUT
#define KX    10
#define PAD   16               // zero rows per batch for AR lags
#define SEQP  (SEQ+PAD)        // 2064

// fp32 -> bf16 round-to-nearest-even
__device__ __forceinline__ u16 f2b(float f) {
    union { float f; uint32_t u; } v; v.f = f;
    uint32_t u = v.u + 0x7fffu + ((v.u >> 16) & 1u);
    return (u16)(u >> 16);
}
__device__ __forceinline__ float b2f(u16 h) {
    union { uint32_t u; float f; } v; v.u = ((uint32_t)h) << 16;
    return v.f;
}

// async global->LDS, 16B per lane; lds dest is wave-uniform base (+lane*16 by HW)
__device__ __forceinline__ void llds16(const u16* g, u16* l) {
    __builtin_amdgcn_global_load_lds(
        (const __attribute__((address_space(1))) uint32_t*)g,
        (__attribute__((address_space(3))) uint32_t*)l, 16, 0, 0);
}

// ---------------- fused prep kernel ----------------
#define PREP_X_END  8256
#define PREP_C_END  10304
#define PREP_M_END  14400

__global__ __launch_bounds__(256) void k_prep(
    const float* __restrict__ x, const float* __restrict__ B,
    const float* __restrict__ C, const float* __restrict__ M,
    u16* __restrict__ Xpad, u16* __restrict__ Btr, u16* __restrict__ Wall)
{
    __shared__ float tile[32][33];
    const int bid = blockIdx.x, tid = threadIdx.x;

    if (bid < PREP_X_END) {
        // inputs (4,2048,1024) f32 -> Xpad (4,2064,1024) bf16, 16 zero rows/batch
        int idx = bid * 256 + tid;
        long e = (long)idx * 4;
        int i = (int)(e & 1023);
        int row = (int)(e >> 10);
        int t = row % SEQP;
        int b = row / SEQP;
        ushort4 o;
        if (t < PAD) {
            o.x = 0; o.y = 0; o.z = 0; o.w = 0;
        } else {
            const float4 v = *(const float4*)(x + (((long)(b * SEQ + (t - PAD)) << 10) + i));
            o.x = f2b(v.x); o.y = f2b(v.y); o.z = f2b(v.z); o.w = f2b(v.w);
        }
        *(ushort4*)(Xpad + ((long)row << 10) + i) = o;
    } else if (bid < PREP_C_END) {
        // transpose+bf16: B -> Btr, C -> Wall group 0
        const int tb = bid - PREP_X_END;
        const float* in = (tb < 1024) ? B : C;
        u16* out = (tb < 1024) ? Btr : Wall;
        int lb = tb & 1023;
        int bx = lb & 31, by = lb >> 5;
        int tx = tid & 31, ty = tid >> 5;
#pragma unroll
        for (int j = 0; j < 4; j++)
            tile[ty + j * 8][tx] = in[(long)(by * 32 + ty + j * 8) * 1024 + bx * 32 + tx];
        __syncthreads();
#pragma unroll
        for (int j = 0; j < 4; j++)
            out[(long)(bx * 32 + ty + j * 8) * 1024 + by * 32 + tx] = f2b(tile[tx][ty + j * 8]);
    } else {
        // M (o,i,k) f32 -> Wall groups 1..10 as [k][o][i] bf16
        int idx = (bid - PREP_C_END) * 256 + tid;
        int o = idx >> 10, i = idx & 1023;
        const float* src = M + (long)idx * KX;
#pragma unroll
        for (int k = 0; k < KX; k++)
            Wall[((long)(k + 1) << 20) + ((long)o << 10) + i] = f2b(src[k]);
    }
}

// ---------------- scan kernels (chunked parallel linear scan) ----------------

__global__ void k_scan1(const u16* __restrict__ U, const float* __restrict__ A,
                        float* __restrict__ F) {
    int s = blockIdx.x * 256 + threadIdx.x;
    int bc = blockIdx.y;
    int b = bc >> 4, c = bc & 15;
    float a = A[s];
    const u16* u = U + (((long)(b * SEQ + c * 128)) << 10) + s;
    float f = 0.f;
#pragma unroll 8
    for (int j = 0; j < 128; j++) f = fmaf(a, f, b2f(u[(long)j << 10]));
    F[((long)bc << 10) + s] = f;
}

__global__ void k_scan2(const float* __restrict__ F, const float* __restrict__ A,
                        const float* __restrict__ h0, float* __restrict__ Carry) {
    int idx = blockIdx.x * 256 + threadIdx.x;
    int b = idx >> 10, s = idx & 1023;
    float a = A[s];
    float a128 = a;
#pragma unroll
    for (int q = 0; q < 7; q++) a128 *= a128;
    float carry = h0[s];
#pragma unroll
    for (int c = 0; c < 16; c++) {
        long off = ((long)(b * 16 + c) << 10) + s;
        Carry[off] = carry;
        carry = fmaf(a128, carry, F[off]);
    }
}

// writes H in-place over U (same element, same thread -> no hazard)
__global__ void k_scan3(u16* __restrict__ U, const float* __restrict__ A,
                        const float* __restrict__ Carry) {
    int s = blockIdx.x * 256 + threadIdx.x;
    int bc = blockIdx.y;
    int b = bc >> 4, c = bc & 15;
    float a = A[s];
    long base = (((long)(b * SEQ + c * 128)) << 10) + s;
    float h = Carry[((long)bc << 10) + s];
#pragma unroll 8
    for (int j = 0; j < 128; j++) {
        h = fmaf(a, h, b2f(U[base + ((long)j << 10)]));
        U[base + ((long)j << 10)] = f2b(h);
    }
}

// ---------------- grouped GEMM, k-outer / g-inner, W direct from global ----------------
// out[r][n] = sum_g sum_k Aop_g[r][k] * W'[g][n][k]
// USE_H=1 (NG=11): g in [0,9] -> A = Xpad rows lag g, W' = Wall group g+1 (M_g);
//                  g = 10     -> A = H rows (lag 0),  W' = Wall group 0 (C^T).
// USE_H=0 (NG=1):  g=0 -> A = Xpad lag 0, W' = W base (Btr).
// Per k0: stage 160-row X slab + H tile once (2 barriers), then NG groups run
// BARRIER-FREE: W fragments are register-double-buffered global loads (L2-fed;
// col0 = bid&7 pins one 2.75 MB W column-slab per XCD -> fits 4 MiB L2).
template<int NG, int USE_H, int BF16_OUT>
__global__ __launch_bounds__(256, 2) void k_gemm(
    void* __restrict__ outv, const u16* __restrict__ Xpad,
    const u16* __restrict__ Hbf, const u16* __restrict__ W)
{
    __shared__ u16 Asl[160 * 64];                    // 20 KB X slab [Xrow0-16, Xrow0+144)
    __shared__ u16 Hsl[(USE_H ? 128 : 1) * 64];      // 16 KB H tile (gemm2 only)

    const int tid  = threadIdx.x;
    const int wave = tid >> 6, lane = tid & 63;
    const int wm = wave >> 1, wn = wave & 1;
    const int quad = lane >> 4, l15 = lane & 15;

    const int bid  = blockIdx.x;                     // 512 blocks, 1-D
    const int col0 = (bid & 7) * 128;                // XCD-pinned column tile
    const int row0 = (bid >> 3) * 128;
    const int bb = row0 >> 11;
    const long Xrow0 = (long)bb * SEQP + PAD + (row0 & (SEQ - 1));
    const long XslabBase = (Xrow0 - 16) << 10;

    f32x4 acc[4][4];
#pragma unroll
    for (int i = 0; i < 4; i++)
#pragma unroll
        for (int j = 0; j < 4; j++)
            acc[i][j] = (f32x4){0.f, 0.f, 0.f, 0.f};

    s16x8 bfrag[2][8];

    for (int k0 = 0; k0 < 1024; k0 += 64) {
        // ---- stage X slab: 160 rows x 64 k, 1280 16B units ----
#pragma unroll
        for (int q = 0; q < 5; q++) {
            int u = wave * 320 + q * 64 + lane;
            int row = u >> 3;
            int kc = (u & 7) ^ (row & 7);
            llds16(Xpad + XslabBase + ((long)row << 10) + k0 + kc * 8,
                   &Asl[(wave * 320 + q * 64) * 8]);
        }
        if (USE_H) {
            const u16* Hb = Hbf + ((long)row0 << 10);
#pragma unroll
            for (int q = 0; q < 4; q++) {
                int u = wave * 256 + q * 64 + lane;
                int row = u >> 3;
                int kc = (u & 7) ^ (row & 7);
                llds16(Hb + ((long)row << 10) + k0 + kc * 8,
                       &Hsl[(wave * 256 + q * 64) * 8]);
            }
        }
        // ---- prefetch W frags for g=0 (register loads, lane reads row n=l15+ni*16) ----
        {
            const int wsel0 = USE_H ? 1 : 0;
            const u16* wp = W + ((long)wsel0 << 20) + ((long)(col0 + wn * 64) << 10) + k0;
#pragma unroll
            for (int ni = 0; ni < 4; ni++)
#pragma unroll
                for (int kk = 0; kk < 2; kk++)
                    bfrag[0][ni * 2 + kk] =
                        *(const s16x8*)(wp + ((l15 + ni * 16) << 10) + kk * 32 + quad * 8);
        }
        __syncthreads();

#pragma unroll
        for (int g = 0; g < NG; g++) {
            // prefetch next group's W while this group computes (no barrier between groups)
            if (g + 1 < NG) {
                const int wsel = USE_H ? ((g + 1 == NG - 1) ? 0 : g + 2) : g + 1;
                const u16* wp = W + ((long)wsel << 20) + ((long)(col0 + wn * 64) << 10) + k0;
#pragma unroll
                for (int ni = 0; ni < 4; ni++)
#pragma unroll
                    for (int kk = 0; kk < 2; kk++)
                        bfrag[(g + 1) & 1][ni * 2 + kk] =
                            *(const s16x8*)(wp + ((l15 + ni * 16) << 10) + kk * 32 + quad * 8);
            }

            const bool isH = USE_H && (g == NG - 1);
            const u16* abase = isH ? Hsl : Asl;
            const int rbase = isH ? 0 : (16 - g);    // slab-local row offset for lag g
            const int r7 = (l15 + rbase) & 7;

            s16x8 af[4][2];
#pragma unroll
            for (int mi = 0; mi < 4; mi++) {
                int arow = rbase + wm * 64 + mi * 16 + l15;
#pragma unroll
                for (int kk = 0; kk < 2; kk++) {
                    int kca = ((kk * 4 + quad) ^ r7) << 3;
                    af[mi][kk] = *(const s16x8*)&abase[arow * 64 + kca];
                }
            }
#pragma unroll
            for (int mi = 0; mi < 4; mi++)
#pragma unroll
                for (int ni = 0; ni < 4; ni++) {
                    acc[mi][ni] = __builtin_amdgcn_mfma_f32_16x16x32_bf16(
                        af[mi][0], bfrag[g & 1][ni * 2 + 0], acc[mi][ni], 0, 0, 0);
                    acc[mi][ni] = __builtin_amdgcn_mfma_f32_16x16x32_bf16(
                        af[mi][1], bfrag[g & 1][ni * 2 + 1], acc[mi][ni], 0, 0, 0);
                }
        }
        __syncthreads();   // all waves done reading slab before next k0 restage
    }

    // ---- epilogue: C/D layout col=lane&15, row=quad*4+reg ----
#pragma unroll
    for (int mi = 0; mi < 4; mi++) {
        int r = row0 + wm * 64 + mi * 16 + quad * 4;
#pragma unroll
        for (int ni = 0; ni < 4; ni++) {
            int c = col0 + wn * 64 + ni * 16 + l15;
            f32x4 v = acc[mi][ni];
            if (BF16_OUT) {
                u16* ob = (u16*)outv;
#pragma unroll
                for (int reg = 0; reg < 4; reg++)
                    ob[((long)(r + reg) << 10) + c] = f2b(v[reg]);
            } else {
                float* of = (float*)outv;
#pragma unroll
                for (int reg = 0; reg < 4; reg++)
                    of[((long)(r + reg) << 10) + c] = v[reg];
            }
        }
    }
}

// ---------------- launch ----------------

extern "C" void kernel_launch(void* const* d_in, const int* in_sizes, int n_in,
                              void* d_out, int out_size, void* d_ws, size_t ws_size,
                              hipStream_t stream) {
    const float* x  = (const float*)d_in[0];   // (4,2048,1024)
    const float* h0 = (const float*)d_in[1];   // (1024,)
    const float* A  = (const float*)d_in[2];   // (1024,)
    const float* B  = (const float*)d_in[3];   // (1024,1024)
    const float* C  = (const float*)d_in[4];   // (1024,1024)
    const float* M  = (const float*)d_in[5];   // (1024,1024,10)
    float* out = (float*)d_out;

    char* ws = (char*)d_ws;
    u16*   Xpad  = (u16*)  (ws);                      // 16,908,288
    u16*   Wall  = (u16*)  (ws + 16908288);           // 23,068,672 (group0 = C^T)
    u16*   Btr   = (u16*)  (ws + 39976960);           // 2,097,152
    u16*   Ubf   = (u16*)  (ws + 42074112);           // 16,777,216 (scan3 overwrites with H)
    float* F     = (float*)(ws + 58851328);           // 262,144
    float* Carry = (float*)(ws + 59113472);           // 262,144  (end ~59.4 MB)

    // fused conversions
    k_prep<<<dim3(PREP_M_END), dim3(256), 0, stream>>>(x, B, C, M, Xpad, Btr, Wall);

    // U = X @ B  (bf16 output)
    k_gemm<1, 0, 1><<<dim3(512), dim3(256), 0, stream>>>(Ubf, Xpad, Ubf, Btr);

    // chunked linear scan; scan3 turns Ubf into Hbf in-place
    k_scan1<<<dim3(4, 64), dim3(256), 0, stream>>>(Ubf, A, F);
    k_scan2<<<dim3(16), dim3(256), 0, stream>>>(F, A, h0, Carry);
    k_scan3<<<dim3(4, 64), dim3(256), 0, stream>>>(Ubf, A, Carry);

    // out = H @ C + sum_k shift_k(X) @ M_k   (11 K-groups)
    k_gemm<11, 1, 0><<<dim3(512), dim3(256), 0, stream>>>(out, Xpad, Ubf, Wall);
}

// Round 5
// 392.071 us; speedup vs baseline: 1.3007x; 1.3007x over previous
//
#include <hip/hip_runtime.h>
#include <stdint.h>

typedef unsigned short u16;
typedef __attribute__((ext_vector_type(4))) float f32x4;
typedef __attribute__((ext_vector_type(8))) short s16x8;

#define BATCH 4
#define SEQ   2048
#define DIM   1024   // D_IN = STATE = D_OUT
#define KX    10
#define PAD   16               // zero rows per batch for AR lags
#define SEQP  (SEQ+PAD)        // 2064

// fp32 -> bf16 round-to-nearest-even
__device__ __forceinline__ u16 f2b(float f) {
    union { float f; uint32_t u; } v; v.f = f;
    uint32_t u = v.u + 0x7fffu + ((v.u >> 16) & 1u);
    return (u16)(u >> 16);
}
__device__ __forceinline__ float b2f(u16 h) {
    union { uint32_t u; float f; } v; v.u = ((uint32_t)h) << 16;
    return v.f;
}

// async global->LDS, 16B per lane; lds dest is wave-uniform base (+lane*16 by HW)
__device__ __forceinline__ void llds16(const u16* g, u16* l) {
    __builtin_amdgcn_global_load_lds(
        (const __attribute__((address_space(1))) uint32_t*)g,
        (__attribute__((address_space(3))) uint32_t*)l, 16, 0, 0);
}

// ---------------- fused prep kernel ----------------
#define PREP_X_END  8256
#define PREP_C_END  10304
#define PREP_M_END  14400

__global__ __launch_bounds__(256) void k_prep(
    const float* __restrict__ x, const float* __restrict__ B,
    const float* __restrict__ C, const float* __restrict__ M,
    u16* __restrict__ Xpad, u16* __restrict__ Btr, u16* __restrict__ Wall)
{
    __shared__ float tile[32][33];
    const int bid = blockIdx.x, tid = threadIdx.x;

    if (bid < PREP_X_END) {
        // inputs (4,2048,1024) f32 -> Xpad (4,2064,1024) bf16, 16 zero rows/batch
        int idx = bid * 256 + tid;
        long e = (long)idx * 4;
        int i = (int)(e & 1023);
        int row = (int)(e >> 10);
        int t = row % SEQP;
        int b = row / SEQP;
        ushort4 o;
        if (t < PAD) {
            o.x = 0; o.y = 0; o.z = 0; o.w = 0;
        } else {
            const float4 v = *(const float4*)(x + (((long)(b * SEQ + (t - PAD)) << 10) + i));
            o.x = f2b(v.x); o.y = f2b(v.y); o.z = f2b(v.z); o.w = f2b(v.w);
        }
        *(ushort4*)(Xpad + ((long)row << 10) + i) = o;
    } else if (bid < PREP_C_END) {
        // transpose+bf16: B -> Btr, C -> Wall group 0
        const int tb = bid - PREP_X_END;
        const float* in = (tb < 1024) ? B : C;
        u16* out = (tb < 1024) ? Btr : Wall;
        int lb = tb & 1023;
        int bx = lb & 31, by = lb >> 5;
        int tx = tid & 31, ty = tid >> 5;
#pragma unroll
        for (int j = 0; j < 4; j++)
            tile[ty + j * 8][tx] = in[(long)(by * 32 + ty + j * 8) * 1024 + bx * 32 + tx];
        __syncthreads();
#pragma unroll
        for (int j = 0; j < 4; j++)
            out[(long)(bx * 32 + ty + j * 8) * 1024 + by * 32 + tx] = f2b(tile[tx][ty + j * 8]);
    } else {
        // M (o,i,k) f32 -> Wall groups 1..10 as [k][o][i] bf16
        int idx = (bid - PREP_C_END) * 256 + tid;
        int o = idx >> 10, i = idx & 1023;
        const float* src = M + (long)idx * KX;
#pragma unroll
        for (int k = 0; k < KX; k++)
            Wall[((long)(k + 1) << 20) + ((long)o << 10) + i] = f2b(src[k]);
    }
}

// ---------------- scan kernels (chunked parallel linear scan) ----------------

__global__ void k_scan1(const u16* __restrict__ U, const float* __restrict__ A,
                        float* __restrict__ F) {
    int s = blockIdx.x * 256 + threadIdx.x;
    int bc = blockIdx.y;
    int b = bc >> 4, c = bc & 15;
    float a = A[s];
    const u16* u = U + (((long)(b * SEQ + c * 128)) << 10) + s;
    float f = 0.f;
#pragma unroll 8
    for (int j = 0; j < 128; j++) f = fmaf(a, f, b2f(u[(long)j << 10]));
    F[((long)bc << 10) + s] = f;
}

__global__ void k_scan2(const float* __restrict__ F, const float* __restrict__ A,
                        const float* __restrict__ h0, float* __restrict__ Carry) {
    int idx = blockIdx.x * 256 + threadIdx.x;
    int b = idx >> 10, s = idx & 1023;
    float a = A[s];
    float a128 = a;
#pragma unroll
    for (int q = 0; q < 7; q++) a128 *= a128;
    float carry = h0[s];
#pragma unroll
    for (int c = 0; c < 16; c++) {
        long off = ((long)(b * 16 + c) << 10) + s;
        Carry[off] = carry;
        carry = fmaf(a128, carry, F[off]);
    }
}

// writes H in-place over U (same element, same thread -> no hazard)
__global__ void k_scan3(u16* __restrict__ U, const float* __restrict__ A,
                        const float* __restrict__ Carry) {
    int s = blockIdx.x * 256 + threadIdx.x;
    int bc = blockIdx.y;
    int b = bc >> 4, c = bc & 15;
    float a = A[s];
    long base = (((long)(b * SEQ + c * 128)) << 10) + s;
    float h = Carry[((long)bc << 10) + s];
#pragma unroll 8
    for (int j = 0; j < 128; j++) {
        h = fmaf(a, h, b2f(U[base + ((long)j << 10)]));
        U[base + ((long)j << 10)] = f2b(h);
    }
}

// ---------------- grouped GEMM, k-outer / g-inner, 256x128 tile, 8 waves ----------------
// out[r][n] = sum_g sum_k Aop_g[r][k] * W'[g][n][k]
// USE_H=1 (NG=11): g in [0,9] -> A = Xpad rows lag g, W' = Wall group g+1 (M_g);
//                  g = 10     -> A = H rows (lag 0),  W' = Wall group 0 (C^T).
// USE_H=0 (NG=1):  g=0 -> A = Xpad lag 0, W' = W base (Btr).
// Per k0: stage 320-row X slab once (all lags), double-buffer 128x64 W per group.
// KSPLIT=2: blocks split K in half; fp32 epilogue uses agent-scope atomic add
// into zeroed d_out (2 blocks/CU = 16 waves/CU hides barrier drains).
template<int NG, int USE_H, int BF16_OUT, int KSPLIT>
__global__ __launch_bounds__(512, 4) void k_gemm(
    void* __restrict__ outv, const u16* __restrict__ Xpad,
    const u16* __restrict__ Hbf, const u16* __restrict__ W)
{
    __shared__ u16 Asl[320 * 64];        // 40 KB X slab [Xrow0-16, Xrow0+304); H uses [0,256)
    __shared__ u16 Wb2[2][128 * 64];     // 2 x 16 KB

    const int tid  = threadIdx.x;
    const int wave = tid >> 6, lane = tid & 63;   // 8 waves
    const int wm = wave >> 1, wn = wave & 1;      // 4 x 2 wave grid, 64x64 each
    const int quad = lane >> 4, l15 = lane & 15;

    const int bid  = blockIdx.x;
    const int col0 = (bid & 7) * 128;             // XCD-pinned column tile
    const int row0 = ((bid >> 3) & 31) * 256;
    const int kh   = (KSPLIT > 1) ? (bid >> 8) : 0;
    const int kbeg = kh * (1024 / KSPLIT);
    const int kend = kbeg + (1024 / KSPLIT);

    const int bb = row0 >> 11;                    // 2048 rows/batch; 256-tiles don't straddle
    const long Xrow0 = (long)bb * SEQP + PAD + (row0 & (SEQ - 1));
    const long XslabBase = (Xrow0 - 16) << 10;

    f32x4 acc[4][4];
#pragma unroll
    for (int i = 0; i < 4; i++)
#pragma unroll
        for (int j = 0; j < 4; j++)
            acc[i][j] = (f32x4){0.f, 0.f, 0.f, 0.f};

    for (int k0 = kbeg; k0 < kend; k0 += 64) {
        // ---- stage X slab: 320 rows x 64 k = 2560 16B units, 5 insts/wave ----
#pragma unroll
        for (int q = 0; q < 5; q++) {
            int u = wave * 320 + q * 64 + lane;
            int row = u >> 3;
            int kc = (u & 7) ^ (row & 7);
            llds16(Xpad + XslabBase + ((long)row << 10) + k0 + kc * 8,
                   &Asl[(wave * 320 + q * 64) * 8]);
        }
        // ---- stage W for g=0 into Wb2[0]: 1024 units, 2 insts/wave ----
        {
            const int wsel0 = USE_H ? 1 : 0;
            const u16* Wg = W + ((long)wsel0 << 20) + ((long)col0 << 10);
#pragma unroll
            for (int q = 0; q < 2; q++) {
                int u = wave * 128 + q * 64 + lane;
                int row = u >> 3;
                int kc = (u & 7) ^ (row & 7);
                llds16(Wg + ((long)row << 10) + k0 + kc * 8,
                       &Wb2[0][(wave * 128 + q * 64) * 8]);
            }
        }
        __syncthreads();

#pragma unroll
        for (int g = 0; g < NG; g++) {
            const bool isH = USE_H && (g == NG - 1);
            if (isH) {
                // X slab fully consumed (loop-tail barrier); overwrite rows [0,256) with H
                const u16* Hb = Hbf + ((long)row0 << 10);
#pragma unroll
                for (int q = 0; q < 4; q++) {
                    int u = wave * 256 + q * 64 + lane;
                    int row = u >> 3;
                    int kc = (u & 7) ^ (row & 7);
                    llds16(Hb + ((long)row << 10) + k0 + kc * 8,
                           &Asl[(wave * 256 + q * 64) * 8]);
                }
                __syncthreads();
            }
            // ---- prefetch next group's W (drained at end-of-g barrier) ----
            if (g + 1 < NG) {
                const int wsel = USE_H ? ((g + 1 == NG - 1) ? 0 : g + 2) : g + 1;
                const u16* Wg = W + ((long)wsel << 20) + ((long)col0 << 10);
                u16* dst = Wb2[(g + 1) & 1];
#pragma unroll
                for (int q = 0; q < 2; q++) {
                    int u = wave * 128 + q * 64 + lane;
                    int row = u >> 3;
                    int kc = (u & 7) ^ (row & 7);
                    llds16(Wg + ((long)row << 10) + k0 + kc * 8,
                           &dst[(wave * 128 + q * 64) * 8]);
                }
            }

            // ---- fragments (swizzled ds_read_b128) ----
            const int rbase = isH ? 0 : (16 - g);    // slab-local row offset for lag g
            const int r7 = (l15 + rbase) & 7;
            const u16* Wrd = Wb2[g & 1];

            s16x8 af[4][2], bfr[4][2];
#pragma unroll
            for (int mi = 0; mi < 4; mi++) {
                int arow = rbase + wm * 64 + mi * 16 + l15;
#pragma unroll
                for (int kk = 0; kk < 2; kk++) {
                    int kca = ((kk * 4 + quad) ^ r7) << 3;
                    int kcb = ((kk * 4 + quad) ^ (l15 & 7)) << 3;
                    af[mi][kk]  = *(const s16x8*)&Asl[arow * 64 + kca];
                    bfr[mi][kk] = *(const s16x8*)&Wrd[(wn * 64 + mi * 16 + l15) * 64 + kcb];
                }
            }
#pragma unroll
            for (int mi = 0; mi < 4; mi++)
#pragma unroll
                for (int ni = 0; ni < 4; ni++) {
                    acc[mi][ni] = __builtin_amdgcn_mfma_f32_16x16x32_bf16(
                        af[mi][0], bfr[ni][0], acc[mi][ni], 0, 0, 0);
                    acc[mi][ni] = __builtin_amdgcn_mfma_f32_16x16x32_bf16(
                        af[mi][1], bfr[ni][1], acc[mi][ni], 0, 0, 0);
                }
            __syncthreads();
        }
    }

    // ---- epilogue: C/D layout col=lane&15, row=quad*4+reg ----
#pragma unroll
    for (int mi = 0; mi < 4; mi++) {
        int r = row0 + wm * 64 + mi * 16 + quad * 4;
#pragma unroll
        for (int ni = 0; ni < 4; ni++) {
            int c = col0 + wn * 64 + ni * 16 + l15;
            f32x4 v = acc[mi][ni];
            if (BF16_OUT) {
                u16* ob = (u16*)outv;
#pragma unroll
                for (int reg = 0; reg < 4; reg++)
                    ob[((long)(r + reg) << 10) + c] = f2b(v[reg]);
            } else if (KSPLIT > 1) {
                float* of = (float*)outv;
#pragma unroll
                for (int reg = 0; reg < 4; reg++)
                    __hip_atomic_fetch_add(of + (((long)(r + reg) << 10) + c), v[reg],
                                           __ATOMIC_RELAXED, __HIP_MEMORY_SCOPE_AGENT);
            } else {
                float* of = (float*)outv;
#pragma unroll
                for (int reg = 0; reg < 4; reg++)
                    of[((long)(r + reg) << 10) + c] = v[reg];
            }
        }
    }
}

// ---------------- launch ----------------

extern "C" void kernel_launch(void* const* d_in, const int* in_sizes, int n_in,
                              void* d_out, int out_size, void* d_ws, size_t ws_size,
                              hipStream_t stream) {
    const float* x  = (const float*)d_in[0];   // (4,2048,1024)
    const float* h0 = (const float*)d_in[1];   // (1024,)
    const float* A  = (const float*)d_in[2];   // (1024,)
    const float* B  = (const float*)d_in[3];   // (1024,1024)
    const float* C  = (const float*)d_in[4];   // (1024,1024)
    const float* M  = (const float*)d_in[5];   // (1024,1024,10)
    float* out = (float*)d_out;

    char* ws = (char*)d_ws;
    u16*   Xpad  = (u16*)  (ws);                      // 16,908,288 + 98,304 slab-overread pad
    u16*   Wall  = (u16*)  (ws + 17006592);           // 23,068,672 (group0 = C^T)
    u16*   Btr   = (u16*)  (ws + 40075264);           // 2,097,152
    u16*   Ubf   = (u16*)  (ws + 42172416);           // 16,777,216 (scan3 overwrites with H)
    float* F     = (float*)(ws + 58949632);           // 262,144
    float* Carry = (float*)(ws + 59211776);           // 262,144  (end ~59.5 MB)

    // fused conversions
    k_prep<<<dim3(PREP_M_END), dim3(256), 0, stream>>>(x, B, C, M, Xpad, Btr, Wall);

    // U = X @ B  (bf16 output), 256 blocks full-K
    k_gemm<1, 0, 1, 1><<<dim3(256), dim3(512), 0, stream>>>(Ubf, Xpad, Ubf, Btr);

    // chunked linear scan; scan3 turns Ubf into Hbf in-place
    k_scan1<<<dim3(4, 64), dim3(256), 0, stream>>>(Ubf, A, F);
    k_scan2<<<dim3(16), dim3(256), 0, stream>>>(F, A, h0, Carry);
    k_scan3<<<dim3(4, 64), dim3(256), 0, stream>>>(Ubf, A, Carry);

    // out = H @ C + sum_k shift_k(X) @ M_k   (11 K-groups, K-split x2, atomic f32)
    hipMemsetAsync(d_out, 0, (size_t)out_size * sizeof(float), stream);
    k_gemm<11, 1, 0, 2><<<dim3(512), dim3(512), 0, stream>>>(out, Xpad, Ubf, Wall);
}

// Round 6
// 338.249 us; speedup vs baseline: 1.5077x; 1.1591x over previous
//
#include <hip/hip_runtime.h>
#include <stdint.h>

typedef unsigned short u16;
typedef __attribute__((ext_vector_type(4))) float f32x4;
typedef __attribute__((ext_vector_type(8))) short s16x8;

#define BATCH 4
#define SEQ   2048
#define DIM   1024   // D_IN = STATE = D_OUT
#define KX    10
#define PAD   16               // zero rows per batch for AR lags
#define SEQP  (SEQ+PAD)        // 2064

// fp32 -> bf16 round-to-nearest-even
__device__ __forceinline__ u16 f2b(float f) {
    union { float f; uint32_t u; } v; v.f = f;
    uint32_t u = v.u + 0x7fffu + ((v.u >> 16) & 1u);
    return (u16)(u >> 16);
}
__device__ __forceinline__ float b2f(u16 h) {
    union { uint32_t u; float f; } v; v.u = ((uint32_t)h) << 16;
    return v.f;
}

// MFMA-fragment swizzle: matrix (n,k) -> element offset such that a wave's
// (16n x 32k) fragment block is 1 KB contiguous, lane (quad*16 + n&15) holding
// 16 contiguous bytes. Layout: [n>>4][k>>5][((k>>3)&3)*16 + (n&15)][k&7]
__device__ __forceinline__ long swz(int n, int k) {
    return (((long)((n >> 4) * 32 + (k >> 5))) << 9)
         + ((((k >> 3) & 3) * 16 + (n & 15)) << 3) + (k & 7);
}

// async global->LDS, 16B per lane; lds dest is wave-uniform base (+lane*16 by HW)
__device__ __forceinline__ void llds16(const u16* g, u16* l) {
    __builtin_amdgcn_global_load_lds(
        (const __attribute__((address_space(1))) uint32_t*)g,
        (__attribute__((address_space(3))) uint32_t*)l, 16, 0, 0);
}

// ---------------- fused prep kernel ----------------
#define PREP_X_END  8256
#define PREP_C_END  10304
#define PREP_M_END  14400

__global__ __launch_bounds__(256) void k_prep(
    const float* __restrict__ x, const float* __restrict__ B,
    const float* __restrict__ C, const float* __restrict__ M,
    u16* __restrict__ Xpad, u16* __restrict__ Btr, u16* __restrict__ Wall)
{
    __shared__ float tile[32][33];
    const int bid = blockIdx.x, tid = threadIdx.x;

    if (bid < PREP_X_END) {
        // inputs (4,2048,1024) f32 -> Xpad (4,2064,1024) bf16, 16 zero rows/batch
        int idx = bid * 256 + tid;
        long e = (long)idx * 4;
        int i = (int)(e & 1023);
        int row = (int)(e >> 10);
        int t = row % SEQP;
        int b = row / SEQP;
        ushort4 o;
        if (t < PAD) {
            o.x = 0; o.y = 0; o.z = 0; o.w = 0;
        } else {
            const float4 v = *(const float4*)(x + (((long)(b * SEQ + (t - PAD)) << 10) + i));
            o.x = f2b(v.x); o.y = f2b(v.y); o.z = f2b(v.z); o.w = f2b(v.w);
        }
        *(ushort4*)(Xpad + ((long)row << 10) + i) = o;
    } else if (bid < PREP_C_END) {
        // transpose+bf16+swizzle: B -> Btr, C -> Wall group 0.  W'[n][k] = in[k][n]
        const int tb = bid - PREP_X_END;
        const float* in = (tb < 1024) ? B : C;
        u16* out = (tb < 1024) ? Btr : Wall;
        int lb = tb & 1023;
        int bx = lb & 31, by = lb >> 5;
        int tx = tid & 31, ty = tid >> 5;
#pragma unroll
        for (int j = 0; j < 4; j++)
            tile[ty + j * 8][tx] = in[(long)(by * 32 + ty + j * 8) * 1024 + bx * 32 + tx];
        __syncthreads();
#pragma unroll
        for (int j = 0; j < 4; j++) {
            int n = bx * 32 + ty + j * 8;
            int k = by * 32 + tx;
            out[swz(n, k)] = f2b(tile[tx][ty + j * 8]);
        }
    } else {
        // M (o,i,k) f32 -> Wall groups 1..10 swizzled: W'[g=k+1][n=o][kdim=i]
        int idx = (bid - PREP_C_END) * 256 + tid;
        int o = idx >> 10, i = idx & 1023;
        const float* src = M + (long)idx * KX;
        long base = swz(o, i);
#pragma unroll
        for (int k = 0; k < KX; k++)
            Wall[(((long)(k + 1)) << 20) + base] = f2b(src[k]);
    }
}

// ---------------- scan kernels (chunked parallel linear scan) ----------------

__global__ void k_scan1(const u16* __restrict__ U, const float* __restrict__ A,
                        float* __restrict__ F) {
    int s = blockIdx.x * 256 + threadIdx.x;
    int bc = blockIdx.y;
    int b = bc >> 4, c = bc & 15;
    float a = A[s];
    const u16* u = U + (((long)(b * SEQ + c * 128)) << 10) + s;
    float f = 0.f;
#pragma unroll 8
    for (int j = 0; j < 128; j++) f = fmaf(a, f, b2f(u[(long)j << 10]));
    F[((long)bc << 10) + s] = f;
}

__global__ void k_scan2(const float* __restrict__ F, const float* __restrict__ A,
                        const float* __restrict__ h0, float* __restrict__ Carry) {
    int idx = blockIdx.x * 256 + threadIdx.x;
    int b = idx >> 10, s = idx & 1023;
    float a = A[s];
    float a128 = a;
#pragma unroll
    for (int q = 0; q < 7; q++) a128 *= a128;
    float carry = h0[s];
#pragma unroll
    for (int c = 0; c < 16; c++) {
        long off = ((long)(b * 16 + c) << 10) + s;
        Carry[off] = carry;
        carry = fmaf(a128, carry, F[off]);
    }
}

// reads U row-major, writes H in MFMA-A-fragment swizzled layout (rows 16-aligned)
__global__ void k_scan3(const u16* __restrict__ U, const float* __restrict__ A,
                        const float* __restrict__ Carry, u16* __restrict__ Hsw) {
    int s = blockIdx.x * 256 + threadIdx.x;
    int bc = blockIdx.y;
    int b = bc >> 4, c = bc & 15;
    float a = A[s];
    int r0 = b * SEQ + c * 128;
    long base = ((long)r0 << 10) + s;
    float h = Carry[((long)bc << 10) + s];
    // swz(r, s) = ((r>>4)*32 + (s>>5))*512 + (((s>>3)&3)*16 + (r&15))*8 + (s&7)
    long sw = (((long)(s >> 5)) << 9) + ((((s >> 3) & 3) * 16) << 3) + (s & 7);
#pragma unroll 8
    for (int j = 0; j < 128; j++) {
        h = fmaf(a, h, b2f(U[base + ((long)j << 10)]));
        int r = r0 + j;
        Hsw[(((long)(r >> 4) * 32) << 9) + ((r & 15) << 3) + sw] = f2b(h);
    }
}

// ---------------- grouped GEMM, k-outer / g-inner ----------------
// A (X lags) from LDS slab; B (W) and H as register fragments loaded coalesced
// from pre-swizzled global memory, double-buffered, BARRIER-FREE group loop.
// 2 barriers per k0 (slab restage only). 128x128 block, 4 waves (2x2 of 64x64).
template<int NG, int USE_H, int BF16_OUT>
__global__ __launch_bounds__(256, 2) void k_gemm(
    void* __restrict__ outv, const u16* __restrict__ Xpad,
    const u16* __restrict__ Hsw, const u16* __restrict__ W)
{
    __shared__ u16 Asl[144 * 64];                    // 18 KB X slab [Xrow0-16, Xrow0+128)

    const int tid  = threadIdx.x;
    const int wave = tid >> 6, lane = tid & 63;
    const int wm = wave >> 1, wn = wave & 1;
    const int quad = lane >> 4, l15 = lane & 15;

    const int bid  = blockIdx.x;                     // 512 blocks
    const int col0 = (bid & 7) * 128;                // XCD-pinned column tile
    const int row0 = (bid >> 3) * 128;
    const int bb = row0 >> 11;
    const long Xrow0 = (long)bb * SEQP + PAD + (row0 & (SEQ - 1));
    const long XslabBase = (Xrow0 - 16) << 10;

    const int n4b = (col0 >> 4) + wn * 4;            // W fragment block-col base
    const int r4b = (row0 >> 4) + wm * 4;            // H fragment block-row base

    f32x4 acc[4][4];
#pragma unroll
    for (int i = 0; i < 4; i++)
#pragma unroll
        for (int j = 0; j < 4; j++)
            acc[i][j] = (f32x4){0.f, 0.f, 0.f, 0.f};

    s16x8 wf[2][8];
    s16x8 hf[USE_H ? 8 : 1];

    for (int k0 = 0; k0 < 1024; k0 += 64) {
        const int kc = k0 >> 5;

        // ---- stage X slab: 144 rows x 64 k = 1152 16B units, 18 wave-insts ----
#pragma unroll
        for (int q = 0; q < 5; q++) {
            int iu = q * 4 + wave;
            if (iu < 18) {
                int u = iu * 64 + lane;
                int row = u >> 3;
                int kcs = (u & 7) ^ (row & 7);
                llds16(Xpad + XslabBase + ((long)row << 10) + k0 + kcs * 8,
                       &Asl[iu * 512]);
            }
        }
        // ---- W frags for g=0 (coalesced 1KB-per-frag register loads) ----
        {
            const u16* Wg = W + (((long)(USE_H ? 1 : 0)) << 20);
#pragma unroll
            for (int ni = 0; ni < 4; ni++)
#pragma unroll
                for (int kk = 0; kk < 2; kk++)
                    wf[0][ni * 2 + kk] = *(const s16x8*)
                        (Wg + (((long)((n4b + ni) * 32 + kc + kk)) << 9) + (lane << 3));
        }
        // ---- H frags for the last group (consumed after 10 groups of cover) ----
        if (USE_H) {
#pragma unroll
            for (int mi = 0; mi < 4; mi++)
#pragma unroll
                for (int kk = 0; kk < 2; kk++)
                    hf[mi * 2 + kk] = *(const s16x8*)
                        (Hsw + (((long)((r4b + mi) * 32 + kc + kk)) << 9) + (lane << 3));
        }
        __syncthreads();                             // slab ready

#pragma unroll
        for (int g = 0; g < NG; g++) {
            // prefetch next group's W into the other register buffer (vmcnt-tracked)
            if (g + 1 < NG) {
                const int wsel = USE_H ? ((g + 1 == NG - 1) ? 0 : g + 2) : g + 1;
                const u16* Wg = W + (((long)wsel) << 20);
#pragma unroll
                for (int ni = 0; ni < 4; ni++)
#pragma unroll
                    for (int kk = 0; kk < 2; kk++)
                        wf[(g + 1) & 1][ni * 2 + kk] = *(const s16x8*)
                            (Wg + (((long)((n4b + ni) * 32 + kc + kk)) << 9) + (lane << 3));
            }

            const bool isH = USE_H && (g == NG - 1);
            s16x8 af[4][2];
            if (isH) {
#pragma unroll
                for (int mi = 0; mi < 4; mi++) {
                    af[mi][0] = hf[mi * 2];
                    af[mi][1] = hf[mi * 2 + 1];
                }
            } else {
                const int rbase = 16 - g;            // slab-local row offset for lag g
                const int r7 = (l15 + rbase) & 7;
#pragma unroll
                for (int mi = 0; mi < 4; mi++) {
                    int arow = rbase + wm * 64 + mi * 16 + l15;
#pragma unroll
                    for (int kk = 0; kk < 2; kk++)
                        af[mi][kk] = *(const s16x8*)
                            &Asl[arow * 64 + (((kk * 4 + quad) ^ r7) << 3)];
                }
            }
#pragma unroll
            for (int mi = 0; mi < 4; mi++)
#pragma unroll
                for (int ni = 0; ni < 4; ni++) {
                    acc[mi][ni] = __builtin_amdgcn_mfma_f32_16x16x32_bf16(
                        af[mi][0], wf[g & 1][ni * 2 + 0], acc[mi][ni], 0, 0, 0);
                    acc[mi][ni] = __builtin_amdgcn_mfma_f32_16x16x32_bf16(
                        af[mi][1], wf[g & 1][ni * 2 + 1], acc[mi][ni], 0, 0, 0);
                }
        }
        __syncthreads();                             // slab reads done before restage
    }

    // ---- epilogue: C/D layout col=lane&15, row=quad*4+reg ----
#pragma unroll
    for (int mi = 0; mi < 4; mi++) {
        int r = row0 + wm * 64 + mi * 16 + quad * 4;
#pragma unroll
        for (int ni = 0; ni < 4; ni++) {
            int c = col0 + wn * 64 + ni * 16 + l15;
            f32x4 v = acc[mi][ni];
            if (BF16_OUT) {
                u16* ob = (u16*)outv;
#pragma unroll
                for (int reg = 0; reg < 4; reg++)
                    ob[((long)(r + reg) << 10) + c] = f2b(v[reg]);
            } else {
                float* of = (float*)outv;
#pragma unroll
                for (int reg = 0; reg < 4; reg++)
                    of[((long)(r + reg) << 10) + c] = v[reg];
            }
        }
    }
}

// ---------------- launch ----------------

extern "C" void kernel_launch(void* const* d_in, const int* in_sizes, int n_in,
                              void* d_out, int out_size, void* d_ws, size_t ws_size,
                              hipStream_t stream) {
    const float* x  = (const float*)d_in[0];   // (4,2048,1024)
    const float* h0 = (const float*)d_in[1];   // (1024,)
    const float* A  = (const float*)d_in[2];   // (1024,)
    const float* B  = (const float*)d_in[3];   // (1024,1024)
    const float* C  = (const float*)d_in[4];   // (1024,1024)
    const float* M  = (const float*)d_in[5];   // (1024,1024,10)
    float* out = (float*)d_out;

    char* ws = (char*)d_ws;
    u16*   Xpad  = (u16*)  (ws);                      // 16,908,288
    u16*   Wall  = (u16*)  (ws + 16908288);           // 23,068,672 (group0 = C^T, swizzled)
    u16*   Btr   = (u16*)  (ws + 39976960);           // 2,097,152  (swizzled)
    u16*   Ubf   = (u16*)  (ws + 42074112);           // 16,777,216 (row-major bf16)
    u16*   Hsw   = (u16*)  (ws + 58851328);           // 16,777,216 (swizzled bf16)
    float* F     = (float*)(ws + 75628544);           // 262,144
    float* Carry = (float*)(ws + 75890688);           // 262,144  (end ~76.2 MB)

    // fused conversions
    k_prep<<<dim3(PREP_M_END), dim3(256), 0, stream>>>(x, B, C, M, Xpad, Btr, Wall);

    // U = X @ B  (bf16 row-major output)
    k_gemm<1, 0, 1><<<dim3(512), dim3(256), 0, stream>>>(Ubf, Xpad, Hsw, Btr);

    // chunked linear scan; scan3 writes swizzled H
    k_scan1<<<dim3(4, 64), dim3(256), 0, stream>>>(Ubf, A, F);
    k_scan2<<<dim3(16), dim3(256), 0, stream>>>(F, A, h0, Carry);
    k_scan3<<<dim3(4, 64), dim3(256), 0, stream>>>(Ubf, A, Carry, Hsw);

    // out = H @ C + sum_k shift_k(X) @ M_k   (11 K-groups)
    k_gemm<11, 1, 0><<<dim3(512), dim3(256), 0, stream>>>(out, Xpad, Hsw, Wall);
}

// Round 7
// 338.121 us; speedup vs baseline: 1.5083x; 1.0004x over previous
//
#include <hip/hip_runtime.h>
#include <stdint.h>

typedef unsigned short u16;
typedef __attribute__((ext_vector_type(4))) float f32x4;
typedef __attribute__((ext_vector_type(8))) short s16x8;

#define BATCH 4
#define SEQ   2048
#define DIM   1024   // D_IN = STATE = D_OUT
#define KX    10
#define PAD   16               // zero rows per batch for AR lags
#define SEQP  (SEQ+PAD)        // 2064

template<int V> struct Int { static constexpr int value = V; };

// fp32 -> bf16 round-to-nearest-even
__device__ __forceinline__ u16 f2b(float f) {
    union { float f; uint32_t u; } v; v.f = f;
    uint32_t u = v.u + 0x7fffu + ((v.u >> 16) & 1u);
    return (u16)(u >> 16);
}
__device__ __forceinline__ float b2f(u16 h) {
    union { uint32_t u; float f; } v; v.u = ((uint32_t)h) << 16;
    return v.f;
}

// MFMA-fragment swizzle: matrix (n,k) -> element offset such that a wave's
// (16n x 32k) fragment block is 1 KB contiguous, lane (quad*16 + n&15) holding
// 16 contiguous bytes. Layout: [n>>4][k>>5][((k>>3)&3)*16 + (n&15)][k&7]
__device__ __forceinline__ long swz(int n, int k) {
    return (((long)((n >> 4) * 32 + (k >> 5))) << 9)
         + ((((k >> 3) & 3) * 16 + (n & 15)) << 3) + (k & 7);
}

// async global->LDS, 16B per lane; lds dest is wave-uniform base (+lane*16 by HW)
__device__ __forceinline__ void llds16(const u16* g, u16* l) {
    __builtin_amdgcn_global_load_lds(
        (const __attribute__((address_space(1))) uint32_t*)g,
        (__attribute__((address_space(3))) uint32_t*)l, 16, 0, 0);
}

// ---------------- fused prep kernel ----------------
#define PREP_X_END  8256
#define PREP_C_END  10304
#define PREP_M_END  14400

__global__ __launch_bounds__(256) void k_prep(
    const float* __restrict__ x, const float* __restrict__ B,
    const float* __restrict__ C, const float* __restrict__ M,
    u16* __restrict__ Xpad, u16* __restrict__ Btr, u16* __restrict__ Wall)
{
    __shared__ float tile[32][33];
    const int bid = blockIdx.x, tid = threadIdx.x;

    if (bid < PREP_X_END) {
        // inputs (4,2048,1024) f32 -> Xpad (4,2064,1024) bf16, 16 zero rows/batch
        int idx = bid * 256 + tid;
        long e = (long)idx * 4;
        int i = (int)(e & 1023);
        int row = (int)(e >> 10);
        int t = row % SEQP;
        int b = row / SEQP;
        ushort4 o;
        if (t < PAD) {
            o.x = 0; o.y = 0; o.z = 0; o.w = 0;
        } else {
            const float4 v = *(const float4*)(x + (((long)(b * SEQ + (t - PAD)) << 10) + i));
            o.x = f2b(v.x); o.y = f2b(v.y); o.z = f2b(v.z); o.w = f2b(v.w);
        }
        *(ushort4*)(Xpad + ((long)row << 10) + i) = o;
    } else if (bid < PREP_C_END) {
        // transpose+bf16+swizzle: B -> Btr, C -> Wall group 0.  W'[n][k] = in[k][n]
        const int tb = bid - PREP_X_END;
        const float* in = (tb < 1024) ? B : C;
        u16* out = (tb < 1024) ? Btr : Wall;
        int lb = tb & 1023;
        int bx = lb & 31, by = lb >> 5;
        int tx = tid & 31, ty = tid >> 5;
#pragma unroll
        for (int j = 0; j < 4; j++)
            tile[ty + j * 8][tx] = in[(long)(by * 32 + ty + j * 8) * 1024 + bx * 32 + tx];
        __syncthreads();
#pragma unroll
        for (int j = 0; j < 4; j++) {
            int n = bx * 32 + ty + j * 8;
            int k = by * 32 + tx;
            out[swz(n, k)] = f2b(tile[tx][ty + j * 8]);
        }
    } else {
        // M (o,i,k) f32 -> Wall groups 1..10 swizzled: W'[g=k+1][n=o][kdim=i]
        int idx = (bid - PREP_C_END) * 256 + tid;
        int o = idx >> 10, i = idx & 1023;
        const float* src = M + (long)idx * KX;
        long base = swz(o, i);
#pragma unroll
        for (int k = 0; k < KX; k++)
            Wall[(((long)(k + 1)) << 20) + base] = f2b(src[k]);
    }
}

// ---------------- scan kernels (chunked parallel linear scan) ----------------

__global__ void k_scan1(const u16* __restrict__ U, const float* __restrict__ A,
                        float* __restrict__ F) {
    int s = blockIdx.x * 256 + threadIdx.x;
    int bc = blockIdx.y;
    int b = bc >> 4, c = bc & 15;
    float a = A[s];
    const u16* u = U + (((long)(b * SEQ + c * 128)) << 10) + s;
    float f = 0.f;
#pragma unroll 8
    for (int j = 0; j < 128; j++) f = fmaf(a, f, b2f(u[(long)j << 10]));
    F[((long)bc << 10) + s] = f;
}

__global__ void k_scan2(const float* __restrict__ F, const float* __restrict__ A,
                        const float* __restrict__ h0, float* __restrict__ Carry) {
    int idx = blockIdx.x * 256 + threadIdx.x;
    int b = idx >> 10, s = idx & 1023;
    float a = A[s];
    float a128 = a;
#pragma unroll
    for (int q = 0; q < 7; q++) a128 *= a128;
    float carry = h0[s];
#pragma unroll
    for (int c = 0; c < 16; c++) {
        long off = ((long)(b * 16 + c) << 10) + s;
        Carry[off] = carry;
        carry = fmaf(a128, carry, F[off]);
    }
}

// reads U row-major, writes H in MFMA-A-fragment swizzled layout (rows 16-aligned)
__global__ void k_scan3(const u16* __restrict__ U, const float* __restrict__ A,
                        const float* __restrict__ Carry, u16* __restrict__ Hsw) {
    int s = blockIdx.x * 256 + threadIdx.x;
    int bc = blockIdx.y;
    int b = bc >> 4, c = bc & 15;
    float a = A[s];
    int r0 = b * SEQ + c * 128;
    long base = ((long)r0 << 10) + s;
    float h = Carry[((long)bc << 10) + s];
    long sw = (((long)(s >> 5)) << 9) + ((((s >> 3) & 3) * 16) << 3) + (s & 7);
#pragma unroll 8
    for (int j = 0; j < 128; j++) {
        h = fmaf(a, h, b2f(U[base + ((long)j << 10)]));
        int r = r0 + j;
        Hsw[(((long)(r >> 4) * 32) << 9) + ((r & 15) << 3) + sw] = f2b(h);
    }
}

// ---------------- grouped GEMM, k-outer / g-inner, double-buffered slab ----------------
// A (X lags) from LDS slab (2 buffers, next-k0 slab in flight during compute);
// B (W) and H as register fragments from pre-swizzled global memory, with a
// CONTINUOUS prefetch chain across groups AND k0 boundaries (parity = (P+g)&1,
// compile-time via 2-unrolled k0 loop; NG odd). One barrier per k0, no exposed
// load latency at it. 128x128 block, 4 waves (2x2 of 64x64).
template<int NG, int USE_H, int BF16_OUT>
__global__ __launch_bounds__(256, 2) void k_gemm(
    void* __restrict__ outv, const u16* __restrict__ Xpad,
    const u16* __restrict__ Hsw, const u16* __restrict__ W)
{
    __shared__ u16 Asl[2][144 * 64];                 // 2 x 18 KB X slab buffers

    const int tid  = threadIdx.x;
    const int wave = tid >> 6, lane = tid & 63;
    const int wm = wave >> 1, wn = wave & 1;
    const int quad = lane >> 4, l15 = lane & 15;

    const int bid  = blockIdx.x;                     // 512 blocks
    const int col0 = (bid & 7) * 128;                // XCD-pinned column tile
    const int row0 = (bid >> 3) * 128;
    const int bb = row0 >> 11;
    const long Xrow0 = (long)bb * SEQP + PAD + (row0 & (SEQ - 1));
    const long XslabBase = (Xrow0 - 16) << 10;

    const int n4b = (col0 >> 4) + wn * 4;            // W fragment block-col base
    const int r4b = (row0 >> 4) + wm * 4;            // H fragment block-row base

    f32x4 acc[4][4];
#pragma unroll
    for (int i = 0; i < 4; i++)
#pragma unroll
        for (int j = 0; j < 4; j++)
            acc[i][j] = (f32x4){0.f, 0.f, 0.f, 0.f};

    s16x8 wf[2][8];
    s16x8 hf[USE_H ? 8 : 1];

    auto stage_slab = [&](int k0, int buf) {
#pragma unroll
        for (int q = 0; q < 5; q++) {
            int iu = q * 4 + wave;
            if (iu < 18) {
                int u = iu * 64 + lane;
                int row = u >> 3;
                int kcs = (u & 7) ^ (row & 7);
                llds16(Xpad + XslabBase + ((long)row << 10) + k0 + kcs * 8,
                       &Asl[buf][iu * 512]);
            }
        }
    };
    auto load_wf = [&](int k0, int g, s16x8* dst) {
        const int wsel = USE_H ? ((g == NG - 1) ? 0 : g + 1) : g;
        const u16* Wg = W + (((long)wsel) << 20);
        const int kc = k0 >> 5;
#pragma unroll
        for (int ni = 0; ni < 4; ni++)
#pragma unroll
            for (int kk = 0; kk < 2; kk++)
                dst[ni * 2 + kk] = *(const s16x8*)
                    (Wg + (((long)((n4b + ni) * 32 + kc + kk)) << 9) + (lane << 3));
    };
    auto load_hf = [&](int k0) {
        const int kc = k0 >> 5;
#pragma unroll
        for (int mi = 0; mi < 4; mi++)
#pragma unroll
            for (int kk = 0; kk < 2; kk++)
                hf[mi * 2 + kk] = *(const s16x8*)
                    (Hsw + (((long)((r4b + mi) * 32 + kc + kk)) << 9) + (lane << 3));
    };

    // ---- preamble: slab + first W + first H ----
    stage_slab(0, 0);
    load_wf(0, 0, wf[0]);
    if (USE_H) load_hf(0);
    __syncthreads();

    auto body = [&](int k0, auto pc) {
        constexpr int P = decltype(pc)::value;       // slab buffer & starting W parity
        const bool more = (k0 + 64) < 1024;
        if (more) stage_slab(k0 + 64, P ^ 1);        // in flight during this k0's MFMAs

#pragma unroll
        for (int g = 0; g < NG; g++) {
            const int p = (P + g) & 1;               // compile-time after unroll (NG odd)
            // continuous W prefetch chain (next group, or next k0's g=0)
            if (g + 1 < NG)      load_wf(k0, g + 1, wf[p ^ 1]);
            else if (more)       load_wf(k0 + 64, 0, wf[p ^ 1]);

            const bool isH = USE_H && (g == NG - 1);
            s16x8 af[4][2];
            if (isH) {
#pragma unroll
                for (int mi = 0; mi < 4; mi++) {
                    af[mi][0] = hf[mi * 2];
                    af[mi][1] = hf[mi * 2 + 1];
                }
                if (more) load_hf(k0 + 64);          // reload right after last use
            } else {
                const int rbase = 16 - g;            // slab-local row offset for lag g
                const int r7 = (l15 + rbase) & 7;
#pragma unroll
                for (int mi = 0; mi < 4; mi++) {
                    int arow = rbase + wm * 64 + mi * 16 + l15;
#pragma unroll
                    for (int kk = 0; kk < 2; kk++)
                        af[mi][kk] = *(const s16x8*)
                            &Asl[P][arow * 64 + (((kk * 4 + quad) ^ r7) << 3)];
                }
            }
#pragma unroll
            for (int mi = 0; mi < 4; mi++)
#pragma unroll
                for (int ni = 0; ni < 4; ni++) {
                    acc[mi][ni] = __builtin_amdgcn_mfma_f32_16x16x32_bf16(
                        af[mi][0], wf[p][ni * 2 + 0], acc[mi][ni], 0, 0, 0);
                    acc[mi][ni] = __builtin_amdgcn_mfma_f32_16x16x32_bf16(
                        af[mi][1], wf[p][ni * 2 + 1], acc[mi][ni], 0, 0, 0);
                }
        }
        __syncthreads();                             // next slab already arrived
    };

    for (int k0 = 0; k0 < 1024; k0 += 128) {
        body(k0,      Int<0>{});
        body(k0 + 64, Int<1>{});
    }

    // ---- epilogue: C/D layout col=lane&15, row=quad*4+reg ----
#pragma unroll
    for (int mi = 0; mi < 4; mi++) {
        int r = row0 + wm * 64 + mi * 16 + quad * 4;
#pragma unroll
        for (int ni = 0; ni < 4; ni++) {
            int c = col0 + wn * 64 + ni * 16 + l15;
            f32x4 v = acc[mi][ni];
            if (BF16_OUT) {
                u16* ob = (u16*)outv;
#pragma unroll
                for (int reg = 0; reg < 4; reg++)
                    ob[((long)(r + reg) << 10) + c] = f2b(v[reg]);
            } else {
                float* of = (float*)outv;
#pragma unroll
                for (int reg = 0; reg < 4; reg++)
                    of[((long)(r + reg) << 10) + c] = v[reg];
            }
        }
    }
}

// ---------------- launch ----------------

extern "C" void kernel_launch(void* const* d_in, const int* in_sizes, int n_in,
                              void* d_out, int out_size, void* d_ws, size_t ws_size,
                              hipStream_t stream) {
    const float* x  = (const float*)d_in[0];   // (4,2048,1024)
    const float* h0 = (const float*)d_in[1];   // (1024,)
    const float* A  = (const float*)d_in[2];   // (1024,)
    const float* B  = (const float*)d_in[3];   // (1024,1024)
    const float* C  = (const float*)d_in[4];   // (1024,1024)
    const float* M  = (const float*)d_in[5];   // (1024,1024,10)
    float* out = (float*)d_out;

    char* ws = (char*)d_ws;
    u16*   Xpad  = (u16*)  (ws);                      // 16,908,288
    u16*   Wall  = (u16*)  (ws + 16908288);           // 23,068,672 (group0 = C^T, swizzled)
    u16*   Btr   = (u16*)  (ws + 39976960);           // 2,097,152  (swizzled)
    u16*   Ubf   = (u16*)  (ws + 42074112);           // 16,777,216 (row-major bf16)
    u16*   Hsw   = (u16*)  (ws + 58851328);           // 16,777,216 (swizzled bf16)
    float* F     = (float*)(ws + 75628544);           // 262,144
    float* Carry = (float*)(ws + 75890688);           // 262,144  (end ~76.2 MB)

    // fused conversions
    k_prep<<<dim3(PREP_M_END), dim3(256), 0, stream>>>(x, B, C, M, Xpad, Btr, Wall);

    // U = X @ B  (bf16 row-major output)
    k_gemm<1, 0, 1><<<dim3(512), dim3(256), 0, stream>>>(Ubf, Xpad, Hsw, Btr);

    // chunked linear scan; scan3 writes swizzled H
    k_scan1<<<dim3(4, 64), dim3(256), 0, stream>>>(Ubf, A, F);
    k_scan2<<<dim3(16), dim3(256), 0, stream>>>(F, A, h0, Carry);
    k_scan3<<<dim3(4, 64), dim3(256), 0, stream>>>(Ubf, A, Carry, Hsw);

    // out = H @ C + sum_k shift_k(X) @ M_k   (11 K-groups)
    k_gemm<11, 1, 0><<<dim3(512), dim3(256), 0, stream>>>(out, Xpad, Hsw, Wall);
}